// Round 1
// baseline (103.294 us; speedup 1.0000x reference)
//
#include <hip/hip_runtime.h>
#include <hip/hip_bf16.h>

#define BATCH   2048
#define NFIELDS 32
#define EMBED   64
#define NPAIRS  496

typedef __attribute__((ext_vector_type(8))) short bf16x8;
typedef __attribute__((ext_vector_type(4))) float f32x4;

__device__ __forceinline__ unsigned short f2bf(float x) {
    unsigned int u = __float_as_uint(x);
    unsigned int r = 0x7fffu + ((u >> 16) & 1u);
    return (unsigned short)((u + r) >> 16);
}
__device__ __forceinline__ float bf2f(unsigned short b) {
    return __uint_as_float(((unsigned int)b) << 16);
}
__device__ __forceinline__ bf16x8 cvt8(const float* p) {
    float4 v0 = *(const float4*)p;
    float4 v1 = *(const float4*)(p + 4);
    bf16x8 o;
    o[0]=(short)f2bf(v0.x); o[1]=(short)f2bf(v0.y); o[2]=(short)f2bf(v0.z); o[3]=(short)f2bf(v0.w);
    o[4]=(short)f2bf(v1.x); o[5]=(short)f2bf(v1.y); o[6]=(short)f2bf(v1.z); o[7]=(short)f2bf(v1.w);
    return o;
}

// Prepass: emb fp32 -> bf16 (same layout); kernel fp32 [i][p][j] -> bf16 [p][i][j]
__global__ __launch_bounds__(256) void convert_prepass(
    const float* __restrict__ emb, const float* __restrict__ kern,
    unsigned short* __restrict__ embB, unsigned short* __restrict__ kernB)
{
    const int EMB4 = BATCH * NFIELDS * EMBED / 4;   // 1048576
    const int KER4 = EMBED * NPAIRS * EMBED / 4;    // 507904
    int t = blockIdx.x * blockDim.x + threadIdx.x;
    if (t < EMB4) {
        float4 v = ((const float4*)emb)[t];
        ushort4 o;
        o.x = f2bf(v.x); o.y = f2bf(v.y); o.z = f2bf(v.z); o.w = f2bf(v.w);
        *(ushort4*)(embB + (size_t)t * 4) = o;
    } else if (t < EMB4 + KER4) {
        int u = t - EMB4;
        int j4   = u & 15;
        int rest = u >> 4;
        int p = rest % NPAIRS;
        int i = rest / NPAIRS;
        float4 v = *(const float4*)(kern + (size_t)i * (NPAIRS*EMBED) + (size_t)p * EMBED + j4*4);
        ushort4 o;
        o.x = f2bf(v.x); o.y = f2bf(v.y); o.z = f2bf(v.z); o.w = f2bf(v.w);
        *(ushort4*)(kernB + (size_t)p * 4096 + i * 64 + j4 * 4) = o;
    }
}

// Main: block = (pair, batch-tile of 128). 4 waves, each wave does 2x 16-batch MFMA tiles.
// out[b,p] = sum_i q[b,i] * (sum_j K_p[i][j] * p[b,j])
template<bool PRE>
__global__ __launch_bounds__(256) void opn_main(
    const void* __restrict__ embP, const void* __restrict__ kernP,
    float* __restrict__ out)
{
    const int pair = blockIdx.x;
    const int bt   = blockIdx.y;

    // decode pair -> (r, c) triu k=1, row-major
    int r = 0, s = 0;
    while (pair >= s + (NFIELDS - 1 - r)) { s += NFIELDS - 1 - r; ++r; }
    const int c = r + 1 + (pair - s);

    __shared__ __align__(16) unsigned short Klds[64][72];      // +8 pad: 2-way banks only
    __shared__ __align__(16) unsigned short Alds[4][16][72];   // per-wave p-tile
    __shared__ __align__(16) unsigned short Qlds[4][16][72];   // per-wave q-tile

    const int tid = threadIdx.x;

    // ---- stage K_pair (64x64 bf16) into LDS ----
    if (PRE) {
        const unsigned short* kb = (const unsigned short*)kernP + (size_t)pair * 4096;
        #pragma unroll
        for (int it = 0; it < 2; ++it) {
            int idx = (it * 256 + tid) * 8;     // 0..4088
            int i = idx >> 6, j = idx & 63;
            *(bf16x8*)&Klds[i][j] = *(const bf16x8*)(kb + idx);
        }
    } else {
        const float* kf = (const float*)kernP;
        #pragma unroll
        for (int it = 0; it < 2; ++it) {
            int idx = (it * 256 + tid) * 8;
            int i = idx >> 6, j = idx & 63;
            const float* src = kf + (size_t)i * (NPAIRS*EMBED) + (size_t)pair * EMBED + j;
            *(bf16x8*)&Klds[i][j] = cvt8(src);
        }
    }
    __syncthreads();

    const int wave = tid >> 6, lane = tid & 63;
    const int col = lane & 15, quad = lane >> 4;

    // Preload B fragments (K^T): B[j][i] = K[i][j]; lane holds B[k=quad*8+t][n=col]
    bf16x8 bfr[4][2];
    #pragma unroll
    for (int nt = 0; nt < 4; ++nt)
        #pragma unroll
        for (int ks = 0; ks < 2; ++ks)
            bfr[nt][ks] = *(const bf16x8*)&Klds[nt*16 + col][ks*32 + quad*8];

    #pragma unroll
    for (int iter = 0; iter < 2; ++iter) {
        const int b0 = bt * 128 + iter * 64 + wave * 16;

        // ---- stage A (field r) and Q (field c): 16 rows x 64 elems each ----
        #pragma unroll
        for (int half = 0; half < 2; ++half) {
            int kk = half * 64 + lane;          // 0..127 chunks of 8
            int row = kk >> 3, seg = kk & 7;
            size_t base = ((size_t)(b0 + row) * NFIELDS) * EMBED + (size_t)seg * 8;
            if (PRE) {
                const unsigned short* eb = (const unsigned short*)embP;
                *(bf16x8*)&Alds[wave][row][seg*8] = *(const bf16x8*)(eb + base + (size_t)r * EMBED);
                *(bf16x8*)&Qlds[wave][row][seg*8] = *(const bf16x8*)(eb + base + (size_t)c * EMBED);
            } else {
                const float* ef = (const float*)embP;
                *(bf16x8*)&Alds[wave][row][seg*8] = cvt8(ef + base + (size_t)r * EMBED);
                *(bf16x8*)&Qlds[wave][row][seg*8] = cvt8(ef + base + (size_t)c * EMBED);
            }
        }
        __syncthreads();

        // A fragments: lane holds A[m=col][k=quad*8+t]
        bf16x8 afr0 = *(const bf16x8*)&Alds[wave][col][quad*8];
        bf16x8 afr1 = *(const bf16x8*)&Alds[wave][col][32 + quad*8];

        float partial[4] = {0.f, 0.f, 0.f, 0.f};
        #pragma unroll
        for (int nt = 0; nt < 4; ++nt) {
            f32x4 acc = {0.f, 0.f, 0.f, 0.f};
            acc = __builtin_amdgcn_mfma_f32_16x16x32_bf16(afr0, bfr[nt][0], acc, 0, 0, 0);
            acc = __builtin_amdgcn_mfma_f32_16x16x32_bf16(afr1, bfr[nt][1], acc, 0, 0, 0);
            // D layout: row m = quad*4+rr (batch), col n = col (i within nt*16)
            #pragma unroll
            for (int rr = 0; rr < 4; ++rr) {
                float qv = bf2f(Qlds[wave][quad*4 + rr][nt*16 + col]);
                partial[rr] += acc[rr] * qv;
            }
        }
        // reduce over the 16 lanes of each quad-group (sum over i)
        #pragma unroll
        for (int mask = 1; mask <= 8; mask <<= 1)
            #pragma unroll
            for (int rr = 0; rr < 4; ++rr)
                partial[rr] += __shfl_xor(partial[rr], mask, 64);

        if (col == 0) {
            #pragma unroll
            for (int rr = 0; rr < 4; ++rr)
                out[(size_t)(b0 + quad*4 + rr) * NPAIRS + pair] = partial[rr];
        }
    }
}

extern "C" void kernel_launch(void* const* d_in, const int* in_sizes, int n_in,
                              void* d_out, int out_size, void* d_ws, size_t ws_size,
                              hipStream_t stream) {
    const float* emb  = (const float*)d_in[0];   // (2048, 32, 64) fp32
    const float* kern = (const float*)d_in[1];   // (64, 496, 64) fp32
    float* out = (float*)d_out;                  // (2048, 1, 496) fp32

    const size_t embElems  = (size_t)BATCH * NFIELDS * EMBED;   // 4194304
    const size_t kernElems = (size_t)EMBED * NPAIRS * EMBED;    // 2031616
    const size_t need = (embElems + kernElems) * sizeof(unsigned short);

    dim3 grid(NPAIRS, BATCH / 128);
    if (ws_size >= need) {
        unsigned short* embB  = (unsigned short*)d_ws;
        unsigned short* kernB = embB + embElems;
        int total4 = (int)((embElems + kernElems) / 4);         // 1556480
        convert_prepass<<<(total4 + 255) / 256, 256, 0, stream>>>(emb, kern, embB, kernB);
        opn_main<true><<<grid, 256, 0, stream>>>((const void*)embB, (const void*)kernB, out);
    } else {
        opn_main<false><<<grid, 256, 0, stream>>>((const void*)emb, (const void*)kern, out);
    }
}